// Round 17
// baseline (762.582 us; speedup 1.0000x reference)
//
#include <hip/hip_runtime.h>

typedef short short8 __attribute__((ext_vector_type(8)));
typedef float f32x4 __attribute__((ext_vector_type(4)));
typedef unsigned short u16x4 __attribute__((ext_vector_type(4)));
typedef unsigned short u16x8 __attribute__((ext_vector_type(8)));

// f32 -> bf16 bits (round-to-nearest-even; finite inputs only)
__device__ __forceinline__ unsigned short f2bf(float x){
  unsigned int u = __float_as_uint(x);
  u = u + 0x7FFFu + ((u >> 16) & 1u);
  return (unsigned short)(u >> 16);
}
__device__ __forceinline__ float bf2f(unsigned short h){
  return __uint_as_float(((unsigned int)h) << 16);
}
// truncation split: hi = trunc16(x), lo = RNE(x - hi). |err| <= 2^-17 |x|.
__device__ __forceinline__ void tsplit(float x, unsigned short& h, unsigned short& l){
  unsigned int u = __float_as_uint(x);
  h = (unsigned short)(u >> 16);
  l = f2bf(x - __uint_as_float(u & 0xFFFF0000u));
}

// ---------------------------------------------------------------- convt
// One-time: split f32 weights into bf16 hi/lo planes AND transpose to [N][K]
// so GEMM B-staging is pure vectorized copies (round-14/15 verified).
__global__ __launch_bounds__(256) void convt(
    const float* __restrict__ S, unsigned short* __restrict__ Dh,
    unsigned short* __restrict__ Dl, int K, int N)
{
  __shared__ unsigned short th[64][33];
  __shared__ unsigned short tl[64][33];
  const int l = blockIdx.z;
  const int k0 = blockIdx.y*32, n0 = blockIdx.x*64;
  const float* src = S + (size_t)l*K*N;
  unsigned short* dh = Dh + (size_t)l*N*K;
  unsigned short* dl = Dl + (size_t)l*N*K;
  const int tid = threadIdx.x;
  #pragma unroll
  for (int p=0;p<2;p++){
    int i = tid + p*256;
    int k = i >> 4;
    int n4 = (i & 15) * 4;
    float4 v = *(const float4*)&src[(size_t)(k0+k)*N + n0 + n4];
    float xs[4] = {v.x,v.y,v.z,v.w};
    #pragma unroll
    for (int e=0;e<4;e++){
      unsigned short hh,ll; tsplit(xs[e],hh,ll);
      th[n4+e][k]=hh; tl[n4+e][k]=ll;
    }
  }
  __syncthreads();
  #pragma unroll
  for (int p=0;p<2;p++){
    int i = tid + p*256;
    int n = i >> 3;
    int k4 = (i & 7) * 4;
    u16x4 h, l_;
    #pragma unroll
    for (int e=0;e<4;e++){ h[e]=th[n][k4+e]; l_[e]=tl[n][k4+e]; }
    *(u16x4*)&dh[(size_t)(n0+n)*K + k0 + k4] = h;
    *(u16x4*)&dl[(size_t)(n0+n)*K + k0 + k4] = l_;
  }
}

// ---------------------------------------------------------------- encoder stage 1
__global__ __launch_bounds__(256) void encoder_s1(
    const float* __restrict__ xc, const float* __restrict__ yc, const float* __restrict__ xt,
    const float* __restrict__ W1, const float* __restrict__ b1,
    float* __restrict__ hid)
{
  __shared__ float zin[10];
  int blk = blockIdx.x; int b = blk>>10; int t = blk & 1023;
  int tid = threadIdx.x;
  if (tid < 10){
    float v;
    if (tid < 8)      v = (t<512) ? xc[((size_t)b*512+t)*8+tid] : xt[((size_t)b*512+(t-512))*8+tid];
    else if (tid==8)  v = (t<512) ? yc[(size_t)b*512+t] : 0.f;
    else              v = (t<512) ? 0.f : 1.f;
    zin[tid]=v;
  }
  __syncthreads();
  float s = b1[tid];
  #pragma unroll
  for (int i=0;i<10;i++) s += zin[i]*W1[i*256+tid];
  hid[(size_t)blk*256 + tid] = fmaxf(s, 0.f);
}

// ---------------------------------------------------------------- layernorm (f32 out; fallback)
__global__ __launch_bounds__(256) void ln_v2(const float* __restrict__ z,
    const float* __restrict__ g, const float* __restrict__ be, float* __restrict__ h)
{
  const int row = blockIdx.x*4 + (threadIdx.x>>6);
  const int lane = threadIdx.x & 63;
  float4 x = *(const float4*)&z[(size_t)row*256 + lane*4];
  float s = (x.x+x.y)+(x.z+x.w);
  #pragma unroll
  for (int off=32; off; off>>=1) s += __shfl_xor(s, off);
  float mu = s * (1.f/256.f);
  float dx = x.x-mu, dy = x.y-mu, dz = x.z-mu, dw = x.w-mu;
  float v = (dx*dx+dy*dy)+(dz*dz+dw*dw);
  #pragma unroll
  for (int off=32; off; off>>=1) v += __shfl_xor(v, off);
  float r = rsqrtf(v*(1.f/256.f) + 1e-5f);
  float4 gv = *(const float4*)&g[lane*4];
  float4 bv = *(const float4*)&be[lane*4];
  float4 o;
  o.x = dx*r*gv.x + bv.x; o.y = dy*r*gv.y + bv.y;
  o.z = dz*r*gv.z + bv.z; o.w = dw*r*gv.w + bv.w;
  *(float4*)&h[(size_t)row*256 + lane*4] = o;
}

// ---------------------------------------------------------------- layernorm -> bf16 hi/lo planes
__global__ __launch_bounds__(256) void ln_v2b(const float* __restrict__ z,
    const float* __restrict__ g, const float* __restrict__ be,
    unsigned short* __restrict__ hh, unsigned short* __restrict__ hl)
{
  const int row = blockIdx.x*4 + (threadIdx.x>>6);
  const int lane = threadIdx.x & 63;
  float4 x = *(const float4*)&z[(size_t)row*256 + lane*4];
  float s = (x.x+x.y)+(x.z+x.w);
  #pragma unroll
  for (int off=32; off; off>>=1) s += __shfl_xor(s, off);
  float mu = s * (1.f/256.f);
  float dx = x.x-mu, dy = x.y-mu, dz = x.z-mu, dw = x.w-mu;
  float v = (dx*dx+dy*dy)+(dz*dz+dw*dw);
  #pragma unroll
  for (int off=32; off; off>>=1) v += __shfl_xor(v, off);
  float r = rsqrtf(v*(1.f/256.f) + 1e-5f);
  float4 gv = *(const float4*)&g[lane*4];
  float4 bv = *(const float4*)&be[lane*4];
  float o[4];
  o[0] = dx*r*gv.x + bv.x; o[1] = dy*r*gv.y + bv.y;
  o[2] = dz*r*gv.z + bv.z; o[3] = dw*r*gv.w + bv.w;
  u16x4 H, L;
  #pragma unroll
  for (int e=0;e<4;e++){ unsigned short a,b2; tsplit(o[e],a,b2); H[e]=a; L[e]=b2; }
  size_t off = (size_t)row*256 + lane*4;
  *(u16x4*)&hh[off] = H;
  *(u16x4*)&hl[off] = L;
}

// ---------------------------------------------------------------- gemm_mfma
// out = EPI(A @ B + bias). BM=128 x BN block, 4 waves, split-bf16 MFMA.
// APRE: 0 = A f32 (in-kernel split) 1 = A bf16 plane (2-term) 2 = A hi/lo planes
// BPRE: 0 = B f32 [K][N] (fallback) 1 = B pre-split pre-transposed [N][K] planes
// EPI : 0 plain f32 ; 1 relu f32 ; 2 +resid f32 ; 3 relu -> bf16 out ;
//       4 qkv-plane out: cols [0,256) -> Q*sc hi/lo planes, [256,512) -> K bf16,
//         [512,768) -> V bf16 (round-17: attn staging becomes pure copies;
//         numerics identical -- same roundings, done in the producer epilogue).
// Frag layouts HW-verified rounds 7-16. No launch_bounds min-waves (R4/R5).
template<int APRE, int BPRE, int EPI, int BN>
__global__ __launch_bounds__(256) void gemm_mfma(
    const float* __restrict__ Af,
    const unsigned short* __restrict__ Abh, const unsigned short* __restrict__ Abl,
    const float* __restrict__ Bf,
    const unsigned short* __restrict__ Bth, const unsigned short* __restrict__ Btl,
    const float* __restrict__ bias, const float* __restrict__ resid,
    float* __restrict__ outf, unsigned short* __restrict__ outb,
    unsigned short* __restrict__ oql, unsigned short* __restrict__ okb,
    unsigned short* __restrict__ ovb,
    int N, int K)
{
  constexpr int LDR = 40;
  constexpr int TC  = BN/32;
  constexpr int NB8 = BN/64;
  __shared__ unsigned short Ah[128*LDR];
  __shared__ unsigned short Al[(APRE==1)?8:(128*LDR)];
  __shared__ unsigned short Bh[BN*LDR], Bl[BN*LDR];

  const int tid = threadIdx.x;
  const int lane = tid & 63, wv = tid >> 6;
  const int wm0 = (wv >> 1) * 64, wn0 = (wv & 1) * (BN/2);
  const int m0 = blockIdx.y * 128, n0 = blockIdx.x * BN;

  const int sar = tid >> 1, sak = (tid & 1) * 16;
  const int cA = ((sar >> 3) & 3) << 3;
  const int sbk = tid >> 3, sbn = (tid & 7) * 16;
  const int cB = ((sbn >> 4) & 3) << 3;
  const int sbn2 = (BN==128) ? (tid >> 1) : (tid >> 2);
  const int sbk2 = (BN==128) ? ((tid & 1) * 16) : ((tid & 3) * 8);
  const int cB2 = ((sbn2 >> 4) & 3) << 3;

  const float* Apf = nullptr; const unsigned short *Aph = nullptr, *Apl = nullptr;
  if constexpr (APRE==0) Apf = Af  + (size_t)(m0 + sar) * K + sak;
  else {
    Aph = Abh + (size_t)(m0 + sar) * K + sak;
    if constexpr (APRE==2) Apl = Abl + (size_t)(m0 + sar) * K + sak;
  }
  const float* Bpf = nullptr; const unsigned short *Bph2 = nullptr, *Bpl2 = nullptr;
  if constexpr (BPRE==0) Bpf = Bf + (size_t)sbk * N + n0 + sbn;
  else {
    Bph2 = Bth + (size_t)(n0 + sbn2) * K + sbk2;
    Bpl2 = Btl + (size_t)(n0 + sbn2) * K + sbk2;
  }

  const int rowb = lane & 15, kb = (lane >> 4) * 8;
  const int NT = K / 32;

  f32x4 acc[4][TC] = {};
  float4 pa[4], pb[4];
  u16x4 qah[4], qal[4];
  u16x8 qb2h[2], qb2l[2];

  auto LOADT = [&](int t){
    #pragma unroll
    for (int g = 0; g < 4; ++g){
      if constexpr (APRE==0) pa[g] = *(const float4*)&Apf[t*32 + g*4];
      else {
        qah[g] = *(const u16x4*)&Aph[t*32 + g*4];
        if constexpr (APRE==2) qal[g] = *(const u16x4*)&Apl[t*32 + g*4];
      }
    }
    if constexpr (BPRE==0){
      #pragma unroll
      for (int g = 0; g < 4; ++g) pb[g] = *(const float4*)&Bpf[(size_t)t*32*N + g*4];
    } else {
      #pragma unroll
      for (int g = 0; g < NB8; ++g){
        qb2h[g] = *(const u16x8*)&Bph2[t*32 + g*8];
        qb2l[g] = *(const u16x8*)&Bpl2[t*32 + g*8];
      }
    }
  };
  auto STAGE = [&](){
    #pragma unroll
    for (int g = 0; g < 4; ++g){
      int idx = sar * LDR + ((sak + g * 4) ^ cA);
      if constexpr (APRE==0){
        float xs[4] = {pa[g].x, pa[g].y, pa[g].z, pa[g].w};
        u16x4 h, l;
        #pragma unroll
        for (int e = 0; e < 4; ++e){ unsigned short hh, ll; tsplit(xs[e], hh, ll); h[e]=hh; l[e]=ll; }
        *(u16x4*)&Ah[idx] = h; *(u16x4*)&Al[idx] = l;
      } else if constexpr (APRE==1){
        *(u16x4*)&Ah[idx] = qah[g];
      } else {
        *(u16x4*)&Ah[idx] = qah[g];
        *(u16x4*)&Al[idx] = qal[g];
      }
    }
    if constexpr (BPRE==0){
      int kx = sbk ^ cB;
      #pragma unroll
      for (int g = 0; g < 4; ++g){
        float xs[4] = {pb[g].x, pb[g].y, pb[g].z, pb[g].w};
        #pragma unroll
        for (int e = 0; e < 4; ++e){
          int n = sbn + g * 4 + e;
          unsigned short hh, ll; tsplit(xs[e], hh, ll);
          Bh[n * LDR + kx] = hh; Bl[n * LDR + kx] = ll;
        }
      }
    } else {
      #pragma unroll
      for (int g = 0; g < NB8; ++g){
        int idx = sbn2 * LDR + ((sbk2 + g*8) ^ cB2);
        *(u16x8*)&Bh[idx] = qb2h[g];
        *(u16x8*)&Bl[idx] = qb2l[g];
      }
    }
  };

  LOADT(0);
  STAGE();
  __syncthreads();

  for (int t = 0; t < NT; ++t){
    if (t + 1 < NT) LOADT(t + 1);
    short8 bh[TC], bl[TC];
    #pragma unroll
    for (int ct = 0; ct < TC; ++ct){
      int n = wn0 + ct * 16 + rowb;
      int idx = n * LDR + (kb ^ (((n >> 4) & 3) << 3));
      bh[ct] = *(const short8*)&Bh[idx];
      bl[ct] = *(const short8*)&Bl[idx];
    }
    #pragma unroll
    for (int rt = 0; rt < 4; ++rt){
      int r = wm0 + rt * 16 + rowb;
      int idx = r * LDR + (kb ^ (((r >> 3) & 3) << 3));
      short8 ah = *(const short8*)&Ah[idx];
      #pragma unroll
      for (int ct = 0; ct < TC; ++ct){
        acc[rt][ct] = __builtin_amdgcn_mfma_f32_16x16x32_bf16(ah, bh[ct], acc[rt][ct], 0, 0, 0);
        acc[rt][ct] = __builtin_amdgcn_mfma_f32_16x16x32_bf16(ah, bl[ct], acc[rt][ct], 0, 0, 0);
      }
      if constexpr (APRE!=1){
        short8 al = *(const short8*)&Al[idx];
        #pragma unroll
        for (int ct = 0; ct < TC; ++ct)
          acc[rt][ct] = __builtin_amdgcn_mfma_f32_16x16x32_bf16(al, bh[ct], acc[rt][ct], 0, 0, 0);
      }
    }
    if (t + 1 < NT){
      __syncthreads();
      STAGE();
      __syncthreads();
    }
  }

  // epilogue: C/D layout col=lane&15, row=(lane>>4)*4+q  (HW-verified)
  const int region = n0 >> 8;       // EPI==4: 0=Q, 1=K, 2=V (BN=64 | 256 ✓)
  #pragma unroll
  for (int ct = 0; ct < TC; ++ct){
    int gc = n0 + wn0 + ct * 16 + rowb;
    float bv = bias[gc];
    int cb = gc & 255;
    #pragma unroll
    for (int rt = 0; rt < 4; ++rt){
      int gr0 = m0 + wm0 + rt * 16 + (lane >> 4) * 4;
      #pragma unroll
      for (int q = 0; q < 4; ++q){
        int gr = gr0 + q;
        float v = acc[rt][ct][q] + bv;
        if constexpr (EPI == 4){
          size_t poff = (size_t)gr*256 + cb;
          if (region == 0){
            unsigned short hh, ll;
            tsplit(v * 0.17677669529663687f, hh, ll);
            outb[poff] = hh; oql[poff] = ll;
          } else if (region == 1){
            okb[poff] = f2bf(v);
          } else {
            ovb[poff] = f2bf(v);
          }
        } else {
          size_t off = (size_t)gr * N + gc;
          if constexpr (EPI == 1) v = fmaxf(v, 0.f);
          if constexpr (EPI == 2) v += resid[off];
          if constexpr (EPI == 3) outb[off] = f2bf(fmaxf(v, 0.f));
          else                    outf[off] = v;
        }
      }
    }
  }
}

// ---------------------------------------------------------------- attention v9 (plane inputs)
// Inputs are attn-native planes from the qkv GEMM epilogue: Qh/Ql (pre-scaled
// hi/lo bf16), Kb, Vb (bf16). Staging = pure u16x8 copies (zero conversions;
// K/V bytes halved vs v8's f32 reads). Structure: 1024 threads, qc=4, 2-term
// QK, 73 KB LDS -- the round-13/16-verified shape. Output: bf16 hi/lo planes.
__global__ __launch_bounds__(1024) void attn_v9(
    const unsigned short* __restrict__ Qh, const unsigned short* __restrict__ Ql,
    const unsigned short* __restrict__ Kb, const unsigned short* __restrict__ Vb,
    unsigned short* __restrict__ oh, unsigned short* __restrict__ ol)
{
  constexpr int LDK = 40;
  constexpr int LDV = 520;
  __shared__ unsigned short Khi[512*LDK];   // 40 KB
  __shared__ unsigned short Vt[32*LDV];     // 32.5 KB
  __shared__ float cbuf[16][16];

  const int tid = threadIdx.x;
  const int qc = blockIdx.x, h = blockIdx.y, b = blockIdx.z;
  const int hoff = h*32;
  const size_t rb = (size_t)b*1024;

  // stage K (copy) and V^T (u16 scatter), keys 0..511
  #pragma unroll
  for (int t = 0; t < 2; ++t){
    int i = tid + t*1024;              // 0..2047
    int row = i >> 2, c8 = (i & 3) * 8;
    *(u16x8*)&Khi[row*LDK + c8] = *(const u16x8*)&Kb[(rb + row)*256 + hoff + c8];
  }
  #pragma unroll
  for (int t = 0; t < 2; ++t){
    int i = tid + t*1024;
    int row = i >> 2, c8 = (i & 3) * 8;
    u16x8 v = *(const u16x8*)&Vb[(rb + row)*256 + hoff + c8];
    #pragma unroll
    for (int e = 0; e < 8; ++e)
      Vt[(c8 + e)*LDV + row] = v[e];
  }

  const int wv = tid >> 6, lane = tid & 63;
  const int g = lane >> 4, r = lane & 15;
  const int q0w = qc*256 + wv*16;

  short8 qh = *(const short8*)&Qh[(rb + q0w + r)*256 + hoff + g*8];
  short8 ql = *(const short8*)&Ql[(rb + q0w + r)*256 + hoff + g*8];
  __syncthreads();

  float m = -1e30f, l = 0.f;
  f32x4 O0 = {0.f,0.f,0.f,0.f}, O1 = {0.f,0.f,0.f,0.f};

  for (int st = 0; st < 16; ++st){
    int key0 = st*32 + (r >> 2)*8 + (r & 3);
    short8 ah0 = *(const short8*)&Khi[key0*LDK + g*8];
    short8 ah1 = *(const short8*)&Khi[(key0+4)*LDK + g*8];
    f32x4 s0 = {0.f,0.f,0.f,0.f}, s1 = {0.f,0.f,0.f,0.f};
    s0 = __builtin_amdgcn_mfma_f32_16x16x32_bf16(ah0, qh, s0, 0,0,0);
    s0 = __builtin_amdgcn_mfma_f32_16x16x32_bf16(ah0, ql, s0, 0,0,0);
    s1 = __builtin_amdgcn_mfma_f32_16x16x32_bf16(ah1, qh, s1, 0,0,0);
    s1 = __builtin_amdgcn_mfma_f32_16x16x32_bf16(ah1, ql, s1, 0,0,0);
    float pv[8] = {s0[0],s0[1],s0[2],s0[3], s1[0],s1[1],s1[2],s1[3]};
    float tm = pv[0];
    #pragma unroll
    for (int j = 1; j < 8; ++j) tm = fmaxf(tm, pv[j]);
    tm = fmaxf(tm, __shfl_xor(tm, 16));
    tm = fmaxf(tm, __shfl_xor(tm, 32));
    float mn = fmaxf(m, tm);
    float ts = 0.f;
    #pragma unroll
    for (int j = 0; j < 8; ++j){ pv[j] = __expf(pv[j] - mn); ts += pv[j]; }
    ts += __shfl_xor(ts, 16);
    ts += __shfl_xor(ts, 32);
    if (__any(mn > m)){
      float corr = __expf(m - mn);
      if (lane < 16) cbuf[wv][lane] = corr;
      asm volatile("s_waitcnt lgkmcnt(0)" ::: "memory");
      f32x4 cf = *(const f32x4*)&cbuf[wv][g*4];
      #pragma unroll
      for (int j = 0; j < 4; ++j){ O0[j] *= cf[j]; O1[j] *= cf[j]; }
      l *= corr;
      m = mn;
    }
    l += ts;
    short8 pa;
    #pragma unroll
    for (int j = 0; j < 8; ++j) pa[j] = (short)f2bf(pv[j]);
    short8 v0 = *(const short8*)&Vt[(size_t)r*LDV + st*32 + g*8];
    short8 v1 = *(const short8*)&Vt[(size_t)(r+16)*LDV + st*32 + g*8];
    O0 = __builtin_amdgcn_mfma_f32_16x16x32_bf16(pa, v0, O0, 0,0,0);
    O1 = __builtin_amdgcn_mfma_f32_16x16x32_bf16(pa, v1, O1, 0,0,0);
  }

  // self-attend tile (targets only): diagonal-masked, K/V from planes
  if (qc >= 2){
    short8 kh8 = *(const short8*)&Kb[(rb + q0w + r)*256 + hoff + g*8];
    f32x4 s = {0.f,0.f,0.f,0.f};
    s = __builtin_amdgcn_mfma_f32_16x16x32_bf16(kh8, qh, s, 0,0,0);
    s = __builtin_amdgcn_mfma_f32_16x16x32_bf16(kh8, ql, s, 0,0,0);
    float pv[8] = {0.f,0.f,0.f,0.f,0.f,0.f,0.f,0.f};
    float tm = -1e30f;
    #pragma unroll
    for (int j = 0; j < 4; ++j){
      bool al_ = (g*4 + j) == r;
      tm = fmaxf(tm, al_ ? s[j] : -1e30f);
    }
    tm = fmaxf(tm, __shfl_xor(tm, 16));
    tm = fmaxf(tm, __shfl_xor(tm, 32));
    float mn = fmaxf(m, tm);
    float ts = 0.f;
    #pragma unroll
    for (int j = 0; j < 4; ++j){
      bool al_ = (g*4 + j) == r;
      pv[j] = al_ ? __expf(s[j] - mn) : 0.f;
      ts += pv[j];
    }
    ts += __shfl_xor(ts, 16);
    ts += __shfl_xor(ts, 32);
    if (__any(mn > m)){
      float corr = __expf(m - mn);
      if (lane < 16) cbuf[wv][lane] = corr;
      asm volatile("s_waitcnt lgkmcnt(0)" ::: "memory");
      f32x4 cf = *(const f32x4*)&cbuf[wv][g*4];
      #pragma unroll
      for (int j = 0; j < 4; ++j){ O0[j] *= cf[j]; O1[j] *= cf[j]; }
      l *= corr;
      m = mn;
    }
    l += ts;
    short8 pa, v0, v1;
    #pragma unroll
    for (int j = 0; j < 8; ++j) pa[j] = (short)f2bf(pv[j]);
    #pragma unroll
    for (int j = 0; j < 4; ++j){
      const unsigned short* vp = &Vb[(rb + q0w + g*4 + j)*256 + hoff];
      v0[j] = (short)vp[r];
      v1[j] = (short)vp[r + 16];
      v0[j+4] = 0; v1[j+4] = 0;
    }
    O0 = __builtin_amdgcn_mfma_f32_16x16x32_bf16(pa, v0, O0, 0,0,0);
    O1 = __builtin_amdgcn_mfma_f32_16x16x32_bf16(pa, v1, O1, 0,0,0);
  }

  float inv = 1.f / l;
  if (lane < 16) cbuf[wv][lane] = inv;
  asm volatile("s_waitcnt lgkmcnt(0)" ::: "memory");
  f32x4 iv = *(const f32x4*)&cbuf[wv][g*4];
  size_t ob = (rb + q0w + g*4)*256 + hoff;
  #pragma unroll
  for (int j = 0; j < 4; ++j){
    unsigned short hh, ll;
    tsplit(O0[j]*iv[j], hh, ll);
    oh[ob + (size_t)j*256 + r] = hh;  ol[ob + (size_t)j*256 + r] = ll;
    tsplit(O1[j]*iv[j], hh, ll);
    oh[ob + (size_t)j*256 + r + 16] = hh;  ol[ob + (size_t)j*256 + r + 16] = ll;
  }
}

// ---------------------------------------------------------------- attention v8 (f32 qkv; fallback)
__global__ __launch_bounds__(1024) void attn_v8(
    const float* __restrict__ qkv, float* __restrict__ o)
{
  constexpr int LDK = 40;
  constexpr int LDV = 520;
  __shared__ unsigned short Khi[512*LDK];
  __shared__ unsigned short Vt[32*LDV];
  __shared__ float cbuf[16][16];

  const int tid = threadIdx.x;
  const int qc = blockIdx.x, h = blockIdx.y, b = blockIdx.z;
  const float* base = qkv + (size_t)b*1024*768;
  const int hoff = h*32;
  const float sc = 0.17677669529663687f;

  #pragma unroll
  for (int t = 0; t < 4; ++t){
    int i = tid + t*1024;
    int row = i >> 3, c4 = (i & 7) * 4;
    float4 kv = *(const float4*)&base[(size_t)row*768 + 256 + hoff + c4];
    float ks[4] = {kv.x, kv.y, kv.z, kv.w};
    u16x4 hk;
    #pragma unroll
    for (int e = 0; e < 4; ++e) hk[e] = f2bf(ks[e]);
    *(u16x4*)&Khi[row*LDK + c4] = hk;
    float4 vv = *(const float4*)&base[(size_t)row*768 + 512 + hoff + c4];
    float vs[4] = {vv.x, vv.y, vv.z, vv.w};
    #pragma unroll
    for (int e = 0; e < 4; ++e)
      Vt[(c4 + e)*LDV + row] = f2bf(vs[e]);
  }

  const int wv = tid >> 6, lane = tid & 63;
  const int g = lane >> 4, r = lane & 15;
  const int q0w = qc*256 + wv*16;

  short8 qh, ql;
  {
    const float* qp = &base[(size_t)(q0w + r)*768 + hoff + g*8];
    float4 a = *(const float4*)qp;
    float4 c = *(const float4*)(qp + 4);
    float xs[8] = {a.x*sc, a.y*sc, a.z*sc, a.w*sc, c.x*sc, c.y*sc, c.z*sc, c.w*sc};
    #pragma unroll
    for (int e = 0; e < 8; ++e){
      unsigned short hb_ = f2bf(xs[e]);
      qh[e] = (short)hb_;
      ql[e] = (short)f2bf(xs[e] - bf2f(hb_));
    }
  }
  __syncthreads();

  float m = -1e30f, l = 0.f;
  f32x4 O0 = {0.f,0.f,0.f,0.f}, O1 = {0.f,0.f,0.f,0.f};

  for (int st = 0; st < 16; ++st){
    int key0 = st*32 + (r >> 2)*8 + (r & 3);
    short8 ah0 = *(const short8*)&Khi[key0*LDK + g*8];
    short8 ah1 = *(const short8*)&Khi[(key0+4)*LDK + g*8];
    f32x4 s0 = {0.f,0.f,0.f,0.f}, s1 = {0.f,0.f,0.f,0.f};
    s0 = __builtin_amdgcn_mfma_f32_16x16x32_bf16(ah0, qh, s0, 0,0,0);
    s0 = __builtin_amdgcn_mfma_f32_16x16x32_bf16(ah0, ql, s0, 0,0,0);
    s1 = __builtin_amdgcn_mfma_f32_16x16x32_bf16(ah1, qh, s1, 0,0,0);
    s1 = __builtin_amdgcn_mfma_f32_16x16x32_bf16(ah1, ql, s1, 0,0,0);
    float pv[8] = {s0[0],s0[1],s0[2],s0[3], s1[0],s1[1],s1[2],s1[3]};
    float tm = pv[0];
    #pragma unroll
    for (int j = 1; j < 8; ++j) tm = fmaxf(tm, pv[j]);
    tm = fmaxf(tm, __shfl_xor(tm, 16));
    tm = fmaxf(tm, __shfl_xor(tm, 32));
    float mn = fmaxf(m, tm);
    float ts = 0.f;
    #pragma unroll
    for (int j = 0; j < 8; ++j){ pv[j] = __expf(pv[j] - mn); ts += pv[j]; }
    ts += __shfl_xor(ts, 16);
    ts += __shfl_xor(ts, 32);
    if (__any(mn > m)){
      float corr = __expf(m - mn);
      if (lane < 16) cbuf[wv][lane] = corr;
      asm volatile("s_waitcnt lgkmcnt(0)" ::: "memory");
      f32x4 cf = *(const f32x4*)&cbuf[wv][g*4];
      #pragma unroll
      for (int j = 0; j < 4; ++j){ O0[j] *= cf[j]; O1[j] *= cf[j]; }
      l *= corr;
      m = mn;
    }
    l += ts;
    short8 pa;
    #pragma unroll
    for (int j = 0; j < 8; ++j) pa[j] = (short)f2bf(pv[j]);
    short8 v0 = *(const short8*)&Vt[(size_t)r*LDV + st*32 + g*8];
    short8 v1 = *(const short8*)&Vt[(size_t)(r+16)*LDV + st*32 + g*8];
    O0 = __builtin_amdgcn_mfma_f32_16x16x32_bf16(pa, v0, O0, 0,0,0);
    O1 = __builtin_amdgcn_mfma_f32_16x16x32_bf16(pa, v1, O1, 0,0,0);
  }

  if (qc >= 2){
    const float* kp = &base[(size_t)(q0w + r)*768 + 256 + hoff + g*8];
    float4 a = *(const float4*)kp;
    float4 c = *(const float4*)(kp + 4);
    float xs[8] = {a.x, a.y, a.z, a.w, c.x, c.y, c.z, c.w};
    short8 kh8;
    #pragma unroll
    for (int e = 0; e < 8; ++e) kh8[e] = (short)f2bf(xs[e]);
    f32x4 s = {0.f,0.f,0.f,0.f};
    s = __builtin_amdgcn_mfma_f32_16x16x32_bf16(kh8, qh, s, 0,0,0);
    s = __builtin_amdgcn_mfma_f32_16x16x32_bf16(kh8, ql, s, 0,0,0);
    float pv[8] = {0.f,0.f,0.f,0.f,0.f,0.f,0.f,0.f};
    float tm = -1e30f;
    #pragma unroll
    for (int j = 0; j < 4; ++j){
      bool al_ = (g*4 + j) == r;
      tm = fmaxf(tm, al_ ? s[j] : -1e30f);
    }
    tm = fmaxf(tm, __shfl_xor(tm, 16));
    tm = fmaxf(tm, __shfl_xor(tm, 32));
    float mn = fmaxf(m, tm);
    float ts = 0.f;
    #pragma unroll
    for (int j = 0; j < 4; ++j){
      bool al_ = (g*4 + j) == r;
      pv[j] = al_ ? __expf(s[j] - mn) : 0.f;
      ts += pv[j];
    }
    ts += __shfl_xor(ts, 16);
    ts += __shfl_xor(ts, 32);
    if (__any(mn > m)){
      float corr = __expf(m - mn);
      if (lane < 16) cbuf[wv][lane] = corr;
      asm volatile("s_waitcnt lgkmcnt(0)" ::: "memory");
      f32x4 cf = *(const f32x4*)&cbuf[wv][g*4];
      #pragma unroll
      for (int j = 0; j < 4; ++j){ O0[j] *= cf[j]; O1[j] *= cf[j]; }
      l *= corr;
      m = mn;
    }
    l += ts;
    short8 pa, v0, v1;
    #pragma unroll
    for (int j = 0; j < 8; ++j) pa[j] = (short)f2bf(pv[j]);
    #pragma unroll
    for (int j = 0; j < 4; ++j){
      const float* vp = &base[(size_t)(q0w + g*4 + j)*768 + 512 + hoff];
      v0[j] = (short)f2bf(vp[r]);
      v1[j] = (short)f2bf(vp[r + 16]);
      v0[j+4] = 0; v1[j+4] = 0;
    }
    O0 = __builtin_amdgcn_mfma_f32_16x16x32_bf16(pa, v0, O0, 0,0,0);
    O1 = __builtin_amdgcn_mfma_f32_16x16x32_bf16(pa, v1, O1, 0,0,0);
  }

  float inv = 1.f / l;
  if (lane < 16) cbuf[wv][lane] = inv;
  asm volatile("s_waitcnt lgkmcnt(0)" ::: "memory");
  f32x4 iv = *(const f32x4*)&cbuf[wv][g*4];
  float* op = o + ((size_t)b*1024 + q0w + g*4)*256 + hoff;
  #pragma unroll
  for (int j = 0; j < 4; ++j){
    op[(size_t)j*256 + r]      = O0[j] * iv[j];
    op[(size_t)j*256 + r + 16] = O1[j] * iv[j];
  }
}

// ---------------------------------------------------------------- launch
extern "C" void kernel_launch(void* const* d_in, const int* in_sizes, int n_in,
                              void* d_out, int out_size, void* d_ws, size_t ws_size,
                              hipStream_t stream)
{
  (void)in_sizes; (void)n_in; (void)out_size;
  const float* xc   = (const float*)d_in[0];
  const float* yc   = (const float*)d_in[1];
  const float* xt   = (const float*)d_in[2];
  const float* eW1  = (const float*)d_in[3];
  const float* eb1  = (const float*)d_in[4];
  const float* eW2  = (const float*)d_in[5];
  const float* eb2  = (const float*)d_in[6];
  const float* Wqkv = (const float*)d_in[7];
  const float* bqkv = (const float*)d_in[8];
  const float* Wo   = (const float*)d_in[9];
  const float* bo   = (const float*)d_in[10];
  const float* ln1g = (const float*)d_in[11];
  const float* ln1b = (const float*)d_in[12];
  const float* ln2g = (const float*)d_in[13];
  const float* ln2b = (const float*)d_in[14];
  const float* Wff1 = (const float*)d_in[15];
  const float* bff1 = (const float*)d_in[16];
  const float* Wff2 = (const float*)d_in[17];
  const float* bff2 = (const float*)d_in[18];

  float* zf = (float*)d_out;            // residual stream [8][1024][256] f32 = 8 MB
  char* ws = (char*)d_ws;

  const size_t MiB = 1024*1024;
  const bool hugews = (ws_size == 0) || (ws_size >= 64*MiB);   // observed ws = 256 MiB

  if (hugews){
    // [0,8) LN planes; [8,24) qkv planes Qh/Ql/Kb/Vb (4 MiB each) / ffh bf16;
    // [32,~50.3) weight planes; [52,60) attn-out planes.
    unsigned short* lnh = (unsigned short*)ws;                      // 4 MiB
    unsigned short* lnl = lnh + 4*MiB/2;
    unsigned short* qQh = (unsigned short*)(ws + 8*MiB);
    unsigned short* qQl = (unsigned short*)(ws + 12*MiB);
    unsigned short* qKb = (unsigned short*)(ws + 16*MiB);
    unsigned short* qVb = (unsigned short*)(ws + 20*MiB);
    unsigned short* ffh_b = (unsigned short*)(ws + 8*MiB);          // reuses qkv planes (dead after attn)
    float*          scratch = (float*)(ws + 8*MiB);                 // enc hid
    unsigned short* W = (unsigned short*)(ws + 32*MiB);
    unsigned short* qkvTh = W;                   // 6*196608 per plane
    unsigned short* qkvTl = W + 1179648;
    unsigned short* woTh  = W + 2359296;         // 6*65536
    unsigned short* woTl  = W + 2752512;
    unsigned short* w1Th  = W + 3145728;         // 6*262144
    unsigned short* w1Tl  = W + 4718592;
    unsigned short* w2Th  = W + 6291456;
    unsigned short* w2Tl  = W + 7864320;
    unsigned short* e2Th  = W + 9437184;         // 65536
    unsigned short* e2Tl  = W + 9502720;
    unsigned short* aoh = (unsigned short*)(ws + 52*MiB);           // 4 MiB
    unsigned short* aol = aoh + 4*MiB/2;

    convt<<<dim3(12,8,6), 256, 0, stream>>>(Wqkv, qkvTh, qkvTl, 256, 768);
    convt<<<dim3(4,8,6),  256, 0, stream>>>(Wo,   woTh,  woTl,  256, 256);
    convt<<<dim3(16,8,6), 256, 0, stream>>>(Wff1, w1Th,  w1Tl,  256, 1024);
    convt<<<dim3(4,32,6), 256, 0, stream>>>(Wff2, w2Th,  w2Tl,  1024, 256);
    convt<<<dim3(4,8,1),  256, 0, stream>>>(eW2,  e2Th,  e2Tl,  256, 256);

    encoder_s1<<<8192, 256, 0, stream>>>(xc, yc, xt, eW1, eb1, scratch);
    gemm_mfma<0,1,0,64><<<dim3(4,64), 256, 0, stream>>>(scratch, nullptr, nullptr,
                                                        nullptr, e2Th, e2Tl,
                                                        eb2, nullptr, zf, nullptr,
                                                        nullptr, nullptr, nullptr, 256, 256);

    for (int l=0; l<6; l++){
      unsigned short* qh_ = qkvTh + (size_t)l*196608;
      unsigned short* ql_ = qkvTl + (size_t)l*196608;
      unsigned short* oh_ = woTh  + (size_t)l*65536;
      unsigned short* olw = woTl  + (size_t)l*65536;
      unsigned short* f1h = w1Th  + (size_t)l*262144;
      unsigned short* f1l = w1Tl  + (size_t)l*262144;
      unsigned short* f2h = w2Th  + (size_t)l*262144;
      unsigned short* f2l = w2Tl  + (size_t)l*262144;

      ln_v2b<<<2048, 256, 0, stream>>>(zf, ln1g+l*256, ln1b+l*256, lnh, lnl);
      // qkv -> attn-native planes (Q*sc hi/lo, K bf16, V bf16)
      gemm_mfma<2,1,4,64><<<dim3(12,64), 256, 0, stream>>>(nullptr, lnh, lnl,
                                                           nullptr, qh_, ql_,
                                                           bqkv+l*768, nullptr, nullptr, qQh,
                                                           qQl, qKb, qVb, 768, 256);
      attn_v9<<<dim3(4,8,8), 1024, 0, stream>>>(qQh, qQl, qKb, qVb, aoh, aol);
      gemm_mfma<2,1,2,64><<<dim3(4,64), 256, 0, stream>>>(nullptr, aoh, aol,
                                                          nullptr, oh_, olw,
                                                          bo+l*256, zf, zf, nullptr,
                                                          nullptr, nullptr, nullptr, 256, 256);
      ln_v2b<<<2048, 256, 0, stream>>>(zf, ln2g+l*256, ln2b+l*256, lnh, lnl);
      gemm_mfma<2,1,3,128><<<dim3(8,64), 256, 0, stream>>>(nullptr, lnh, lnl,
                                                           nullptr, f1h, f1l,
                                                           bff1+l*1024, nullptr, nullptr, ffh_b,
                                                           nullptr, nullptr, nullptr, 1024, 256);
      gemm_mfma<1,1,2,64><<<dim3(4,64), 256, 0, stream>>>(nullptr, ffh_b, nullptr,
                                                          nullptr, f2h, f2l,
                                                          bff2+l*256, zf, zf, nullptr,
                                                          nullptr, nullptr, nullptr, 256, 1024);
    }
  } else {
    // conservative fallback: all-f32 path (in-kernel split), chunked scratch
    float* hb      = (float*)(ws);
    float* scratch = (float*)(ws + 8*MiB);
    encoder_s1<<<8192, 256, 0, stream>>>(xc, yc, xt, eW1, eb1, hb);
    gemm_mfma<0,0,0,128><<<dim3(2,64), 256, 0, stream>>>(hb, nullptr, nullptr, eW2, nullptr, nullptr,
                                                         eb2, nullptr, zf, nullptr,
                                                         nullptr, nullptr, nullptr, 256, 256);
    for (int l=0; l<6; l++){
      const float* Wq = Wqkv + (size_t)l*256*768;
      const float* Wl = Wo   + (size_t)l*256*256;
      const float* W1 = Wff1 + (size_t)l*256*1024;
      const float* W2 = Wff2 + (size_t)l*1024*256;

      ln_v2<<<2048, 256, 0, stream>>>(zf, ln1g+l*256, ln1b+l*256, hb);
      for (int c=0; c<4; c++){
        float* hrows = hb + (size_t)c*2048*256;
        gemm_mfma<0,0,0,128><<<dim3(6,16), 256, 0, stream>>>(hrows, nullptr, nullptr, Wq, nullptr, nullptr,
                                                             bqkv+l*768, nullptr, scratch, nullptr,
                                                             nullptr, nullptr, nullptr, 768, 256);
        attn_v8<<<dim3(4,8,2), 1024, 0, stream>>>(scratch, hrows);
      }
      gemm_mfma<0,0,2,128><<<dim3(2,64), 256, 0, stream>>>(hb, nullptr, nullptr, Wl, nullptr, nullptr,
                                                           bo+l*256, zf, zf, nullptr,
                                                           nullptr, nullptr, nullptr, 256, 256);
      ln_v2<<<2048, 256, 0, stream>>>(zf, ln2g+l*256, ln2b+l*256, hb);
      for (int c=0; c<4; c++){
        float* hrows = hb + (size_t)c*2048*256;
        float* zrows = zf + (size_t)c*2048*256;
        gemm_mfma<0,0,1,128><<<dim3(8,16), 256, 0, stream>>>(hrows, nullptr, nullptr, W1, nullptr, nullptr,
                                                             bff1+l*1024, nullptr, scratch, nullptr,
                                                             nullptr, nullptr, nullptr, 1024, 256);
        gemm_mfma<0,0,2,128><<<dim3(2,16), 256, 0, stream>>>(scratch, nullptr, nullptr, W2, nullptr, nullptr,
                                                             bff2+l*256, zrows, zrows, nullptr,
                                                             nullptr, nullptr, nullptr, 256, 1024);
      }
    }
  }
}

// Round 18
// 757.949 us; speedup vs baseline: 1.0061x; 1.0061x over previous
//
#include <hip/hip_runtime.h>

typedef short short8 __attribute__((ext_vector_type(8)));
typedef float f32x4 __attribute__((ext_vector_type(4)));
typedef unsigned short u16x4 __attribute__((ext_vector_type(4)));
typedef unsigned short u16x8 __attribute__((ext_vector_type(8)));

// f32 -> bf16 bits (round-to-nearest-even; finite inputs only)
__device__ __forceinline__ unsigned short f2bf(float x){
  unsigned int u = __float_as_uint(x);
  u = u + 0x7FFFu + ((u >> 16) & 1u);
  return (unsigned short)(u >> 16);
}
__device__ __forceinline__ float bf2f(unsigned short h){
  return __uint_as_float(((unsigned int)h) << 16);
}
// truncation split: hi = trunc16(x), lo = RNE(x - hi). |err| <= 2^-17 |x|.
__device__ __forceinline__ void tsplit(float x, unsigned short& h, unsigned short& l){
  unsigned int u = __float_as_uint(x);
  h = (unsigned short)(u >> 16);
  l = f2bf(x - __uint_as_float(u & 0xFFFF0000u));
}

// ---------------------------------------------------------------- convt
// One-time: split f32 weights into bf16 hi/lo planes AND transpose to [N][K]
// so GEMM B-staging is pure vectorized copies (round-14/15 verified).
__global__ __launch_bounds__(256) void convt(
    const float* __restrict__ S, unsigned short* __restrict__ Dh,
    unsigned short* __restrict__ Dl, int K, int N)
{
  __shared__ unsigned short th[64][33];
  __shared__ unsigned short tl[64][33];
  const int l = blockIdx.z;
  const int k0 = blockIdx.y*32, n0 = blockIdx.x*64;
  const float* src = S + (size_t)l*K*N;
  unsigned short* dh = Dh + (size_t)l*N*K;
  unsigned short* dl = Dl + (size_t)l*N*K;
  const int tid = threadIdx.x;
  #pragma unroll
  for (int p=0;p<2;p++){
    int i = tid + p*256;
    int k = i >> 4;
    int n4 = (i & 15) * 4;
    float4 v = *(const float4*)&src[(size_t)(k0+k)*N + n0 + n4];
    float xs[4] = {v.x,v.y,v.z,v.w};
    #pragma unroll
    for (int e=0;e<4;e++){
      unsigned short hh,ll; tsplit(xs[e],hh,ll);
      th[n4+e][k]=hh; tl[n4+e][k]=ll;
    }
  }
  __syncthreads();
  #pragma unroll
  for (int p=0;p<2;p++){
    int i = tid + p*256;
    int n = i >> 3;
    int k4 = (i & 7) * 4;
    u16x4 h, l_;
    #pragma unroll
    for (int e=0;e<4;e++){ h[e]=th[n][k4+e]; l_[e]=tl[n][k4+e]; }
    *(u16x4*)&dh[(size_t)(n0+n)*K + k0 + k4] = h;
    *(u16x4*)&dl[(size_t)(n0+n)*K + k0 + k4] = l_;
  }
}

// ---------------------------------------------------------------- encoder stage 1
__global__ __launch_bounds__(256) void encoder_s1(
    const float* __restrict__ xc, const float* __restrict__ yc, const float* __restrict__ xt,
    const float* __restrict__ W1, const float* __restrict__ b1,
    float* __restrict__ hid)
{
  __shared__ float zin[10];
  int blk = blockIdx.x; int b = blk>>10; int t = blk & 1023;
  int tid = threadIdx.x;
  if (tid < 10){
    float v;
    if (tid < 8)      v = (t<512) ? xc[((size_t)b*512+t)*8+tid] : xt[((size_t)b*512+(t-512))*8+tid];
    else if (tid==8)  v = (t<512) ? yc[(size_t)b*512+t] : 0.f;
    else              v = (t<512) ? 0.f : 1.f;
    zin[tid]=v;
  }
  __syncthreads();
  float s = b1[tid];
  #pragma unroll
  for (int i=0;i<10;i++) s += zin[i]*W1[i*256+tid];
  hid[(size_t)blk*256 + tid] = fmaxf(s, 0.f);
}

// ---------------------------------------------------------------- layernorm (f32 out; fallback)
__global__ __launch_bounds__(256) void ln_v2(const float* __restrict__ z,
    const float* __restrict__ g, const float* __restrict__ be, float* __restrict__ h)
{
  const int row = blockIdx.x*4 + (threadIdx.x>>6);
  const int lane = threadIdx.x & 63;
  float4 x = *(const float4*)&z[(size_t)row*256 + lane*4];
  float s = (x.x+x.y)+(x.z+x.w);
  #pragma unroll
  for (int off=32; off; off>>=1) s += __shfl_xor(s, off);
  float mu = s * (1.f/256.f);
  float dx = x.x-mu, dy = x.y-mu, dz = x.z-mu, dw = x.w-mu;
  float v = (dx*dx+dy*dy)+(dz*dz+dw*dw);
  #pragma unroll
  for (int off=32; off; off>>=1) v += __shfl_xor(v, off);
  float r = rsqrtf(v*(1.f/256.f) + 1e-5f);
  float4 gv = *(const float4*)&g[lane*4];
  float4 bv = *(const float4*)&be[lane*4];
  float4 o;
  o.x = dx*r*gv.x + bv.x; o.y = dy*r*gv.y + bv.y;
  o.z = dz*r*gv.z + bv.z; o.w = dw*r*gv.w + bv.w;
  *(float4*)&h[(size_t)row*256 + lane*4] = o;
}

// ---------------------------------------------------------------- layernorm -> bf16 hi/lo planes
__global__ __launch_bounds__(256) void ln_v2b(const float* __restrict__ z,
    const float* __restrict__ g, const float* __restrict__ be,
    unsigned short* __restrict__ hh, unsigned short* __restrict__ hl)
{
  const int row = blockIdx.x*4 + (threadIdx.x>>6);
  const int lane = threadIdx.x & 63;
  float4 x = *(const float4*)&z[(size_t)row*256 + lane*4];
  float s = (x.x+x.y)+(x.z+x.w);
  #pragma unroll
  for (int off=32; off; off>>=1) s += __shfl_xor(s, off);
  float mu = s * (1.f/256.f);
  float dx = x.x-mu, dy = x.y-mu, dz = x.z-mu, dw = x.w-mu;
  float v = (dx*dx+dy*dy)+(dz*dz+dw*dw);
  #pragma unroll
  for (int off=32; off; off>>=1) v += __shfl_xor(v, off);
  float r = rsqrtf(v*(1.f/256.f) + 1e-5f);
  float4 gv = *(const float4*)&g[lane*4];
  float4 bv = *(const float4*)&be[lane*4];
  float o[4];
  o[0] = dx*r*gv.x + bv.x; o[1] = dy*r*gv.y + bv.y;
  o[2] = dz*r*gv.z + bv.z; o[3] = dw*r*gv.w + bv.w;
  u16x4 H, L;
  #pragma unroll
  for (int e=0;e<4;e++){ unsigned short a,b2; tsplit(o[e],a,b2); H[e]=a; L[e]=b2; }
  size_t off = (size_t)row*256 + lane*4;
  *(u16x4*)&hh[off] = H;
  *(u16x4*)&hl[off] = L;
}

// ---------------------------------------------------------------- gemm_mfma
// out = EPI(A @ B + bias). BM=128 x BN block, 4 waves, split-bf16 MFMA.
// APRE: 0 = A f32 (in-kernel split) 1 = A bf16 plane (2-term) 2 = A hi/lo planes
// BPRE: 0 = B f32 [K][N] (fallback) 1 = B pre-split pre-transposed [N][K] planes
// EPI : 0 plain f32 ; 1 relu f32 ; 2 +resid f32 ; 3 relu -> bf16 out ;
//       4 qkv-plane out (Q*sc hi/lo, K bf16, V bf16 by column region)
// Frag layouts HW-verified rounds 7-17. No launch_bounds min-waves (R4/R5).
template<int APRE, int BPRE, int EPI, int BN>
__global__ __launch_bounds__(256) void gemm_mfma(
    const float* __restrict__ Af,
    const unsigned short* __restrict__ Abh, const unsigned short* __restrict__ Abl,
    const float* __restrict__ Bf,
    const unsigned short* __restrict__ Bth, const unsigned short* __restrict__ Btl,
    const float* __restrict__ bias, const float* __restrict__ resid,
    float* __restrict__ outf, unsigned short* __restrict__ outb,
    unsigned short* __restrict__ oql, unsigned short* __restrict__ okb,
    unsigned short* __restrict__ ovb,
    int N, int K)
{
  constexpr int LDR = 40;
  constexpr int TC  = BN/32;
  constexpr int NB8 = BN/64;
  __shared__ unsigned short Ah[128*LDR];
  __shared__ unsigned short Al[(APRE==1)?8:(128*LDR)];
  __shared__ unsigned short Bh[BN*LDR], Bl[BN*LDR];

  const int tid = threadIdx.x;
  const int lane = tid & 63, wv = tid >> 6;
  const int wm0 = (wv >> 1) * 64, wn0 = (wv & 1) * (BN/2);
  const int m0 = blockIdx.y * 128, n0 = blockIdx.x * BN;

  const int sar = tid >> 1, sak = (tid & 1) * 16;
  const int cA = ((sar >> 3) & 3) << 3;
  const int sbk = tid >> 3, sbn = (tid & 7) * 16;
  const int cB = ((sbn >> 4) & 3) << 3;
  const int sbn2 = (BN==128) ? (tid >> 1) : (tid >> 2);
  const int sbk2 = (BN==128) ? ((tid & 1) * 16) : ((tid & 3) * 8);
  const int cB2 = ((sbn2 >> 4) & 3) << 3;

  const float* Apf = nullptr; const unsigned short *Aph = nullptr, *Apl = nullptr;
  if constexpr (APRE==0) Apf = Af  + (size_t)(m0 + sar) * K + sak;
  else {
    Aph = Abh + (size_t)(m0 + sar) * K + sak;
    if constexpr (APRE==2) Apl = Abl + (size_t)(m0 + sar) * K + sak;
  }
  const float* Bpf = nullptr; const unsigned short *Bph2 = nullptr, *Bpl2 = nullptr;
  if constexpr (BPRE==0) Bpf = Bf + (size_t)sbk * N + n0 + sbn;
  else {
    Bph2 = Bth + (size_t)(n0 + sbn2) * K + sbk2;
    Bpl2 = Btl + (size_t)(n0 + sbn2) * K + sbk2;
  }

  const int rowb = lane & 15, kb = (lane >> 4) * 8;
  const int NT = K / 32;

  f32x4 acc[4][TC] = {};
  float4 pa[4], pb[4];
  u16x4 qah[4], qal[4];
  u16x8 qb2h[2], qb2l[2];

  auto LOADT = [&](int t){
    #pragma unroll
    for (int g = 0; g < 4; ++g){
      if constexpr (APRE==0) pa[g] = *(const float4*)&Apf[t*32 + g*4];
      else {
        qah[g] = *(const u16x4*)&Aph[t*32 + g*4];
        if constexpr (APRE==2) qal[g] = *(const u16x4*)&Apl[t*32 + g*4];
      }
    }
    if constexpr (BPRE==0){
      #pragma unroll
      for (int g = 0; g < 4; ++g) pb[g] = *(const float4*)&Bpf[(size_t)t*32*N + g*4];
    } else {
      #pragma unroll
      for (int g = 0; g < NB8; ++g){
        qb2h[g] = *(const u16x8*)&Bph2[t*32 + g*8];
        qb2l[g] = *(const u16x8*)&Bpl2[t*32 + g*8];
      }
    }
  };
  auto STAGE = [&](){
    #pragma unroll
    for (int g = 0; g < 4; ++g){
      int idx = sar * LDR + ((sak + g * 4) ^ cA);
      if constexpr (APRE==0){
        float xs[4] = {pa[g].x, pa[g].y, pa[g].z, pa[g].w};
        u16x4 h, l;
        #pragma unroll
        for (int e = 0; e < 4; ++e){ unsigned short hh, ll; tsplit(xs[e], hh, ll); h[e]=hh; l[e]=ll; }
        *(u16x4*)&Ah[idx] = h; *(u16x4*)&Al[idx] = l;
      } else if constexpr (APRE==1){
        *(u16x4*)&Ah[idx] = qah[g];
      } else {
        *(u16x4*)&Ah[idx] = qah[g];
        *(u16x4*)&Al[idx] = qal[g];
      }
    }
    if constexpr (BPRE==0){
      int kx = sbk ^ cB;
      #pragma unroll
      for (int g = 0; g < 4; ++g){
        float xs[4] = {pb[g].x, pb[g].y, pb[g].z, pb[g].w};
        #pragma unroll
        for (int e = 0; e < 4; ++e){
          int n = sbn + g * 4 + e;
          unsigned short hh, ll; tsplit(xs[e], hh, ll);
          Bh[n * LDR + kx] = hh; Bl[n * LDR + kx] = ll;
        }
      }
    } else {
      #pragma unroll
      for (int g = 0; g < NB8; ++g){
        int idx = sbn2 * LDR + ((sbk2 + g*8) ^ cB2);
        *(u16x8*)&Bh[idx] = qb2h[g];
        *(u16x8*)&Bl[idx] = qb2l[g];
      }
    }
  };

  LOADT(0);
  STAGE();
  __syncthreads();

  for (int t = 0; t < NT; ++t){
    if (t + 1 < NT) LOADT(t + 1);
    short8 bh[TC], bl[TC];
    #pragma unroll
    for (int ct = 0; ct < TC; ++ct){
      int n = wn0 + ct * 16 + rowb;
      int idx = n * LDR + (kb ^ (((n >> 4) & 3) << 3));
      bh[ct] = *(const short8*)&Bh[idx];
      bl[ct] = *(const short8*)&Bl[idx];
    }
    #pragma unroll
    for (int rt = 0; rt < 4; ++rt){
      int r = wm0 + rt * 16 + rowb;
      int idx = r * LDR + (kb ^ (((r >> 3) & 3) << 3));
      short8 ah = *(const short8*)&Ah[idx];
      #pragma unroll
      for (int ct = 0; ct < TC; ++ct){
        acc[rt][ct] = __builtin_amdgcn_mfma_f32_16x16x32_bf16(ah, bh[ct], acc[rt][ct], 0, 0, 0);
        acc[rt][ct] = __builtin_amdgcn_mfma_f32_16x16x32_bf16(ah, bl[ct], acc[rt][ct], 0, 0, 0);
      }
      if constexpr (APRE!=1){
        short8 al = *(const short8*)&Al[idx];
        #pragma unroll
        for (int ct = 0; ct < TC; ++ct)
          acc[rt][ct] = __builtin_amdgcn_mfma_f32_16x16x32_bf16(al, bh[ct], acc[rt][ct], 0, 0, 0);
      }
    }
    if (t + 1 < NT){
      __syncthreads();
      STAGE();
      __syncthreads();
    }
  }

  // epilogue: C/D layout col=lane&15, row=(lane>>4)*4+q  (HW-verified)
  const int region = n0 >> 8;
  #pragma unroll
  for (int ct = 0; ct < TC; ++ct){
    int gc = n0 + wn0 + ct * 16 + rowb;
    float bv = bias[gc];
    int cb = gc & 255;
    #pragma unroll
    for (int rt = 0; rt < 4; ++rt){
      int gr0 = m0 + wm0 + rt * 16 + (lane >> 4) * 4;
      #pragma unroll
      for (int q = 0; q < 4; ++q){
        int gr = gr0 + q;
        float v = acc[rt][ct][q] + bv;
        if constexpr (EPI == 4){
          size_t poff = (size_t)gr*256 + cb;
          if (region == 0){
            unsigned short hh, ll;
            tsplit(v * 0.17677669529663687f, hh, ll);
            outb[poff] = hh; oql[poff] = ll;
          } else if (region == 1){
            okb[poff] = f2bf(v);
          } else {
            ovb[poff] = f2bf(v);
          }
        } else {
          size_t off = (size_t)gr * N + gc;
          if constexpr (EPI == 1) v = fmaxf(v, 0.f);
          if constexpr (EPI == 2) v += resid[off];
          if constexpr (EPI == 3) outb[off] = f2bf(fmaxf(v, 0.f));
          else                    outf[off] = v;
        }
      }
    }
  }
}

// ---------------------------------------------------------------- attention v10 (plane inputs, 2 blocks/CU)
// Round-18: 512-thread blocks, qc=8 -> 512 blocks = 2 blocks/CU (v9 was 256
// blocks = 1/CU: zero cross-block overlap, exposed staging/drain). The qc=8
// staging duplication that killed v7 cost ~8us of f32 conversions; with plane
// inputs it's ~1us of u16 copies. Same per-CU wave count (16), but two
// independent blocks overlap staging/epilogue with MFMA. Math identical to v9.
__global__ __launch_bounds__(512) void attn_v10(
    const unsigned short* __restrict__ Qh, const unsigned short* __restrict__ Ql,
    const unsigned short* __restrict__ Kb, const unsigned short* __restrict__ Vb,
    unsigned short* __restrict__ oh, unsigned short* __restrict__ ol)
{
  constexpr int LDK = 40;
  constexpr int LDV = 520;
  __shared__ unsigned short Khi[512*LDK];   // 40 KB
  __shared__ unsigned short Vt[32*LDV];     // 32.5 KB
  __shared__ float cbuf[8][16];

  const int tid = threadIdx.x;
  const int qc = blockIdx.x, h = blockIdx.y, b = blockIdx.z;
  const int hoff = h*32;
  const size_t rb = (size_t)b*1024;

  // stage K (copy) and V^T (u16 scatter), keys 0..511
  #pragma unroll
  for (int t = 0; t < 4; ++t){
    int i = tid + t*512;               // 0..2047
    int row = i >> 2, c8 = (i & 3) * 8;
    *(u16x8*)&Khi[row*LDK + c8] = *(const u16x8*)&Kb[(rb + row)*256 + hoff + c8];
  }
  #pragma unroll
  for (int t = 0; t < 4; ++t){
    int i = tid + t*512;
    int row = i >> 2, c8 = (i & 3) * 8;
    u16x8 v = *(const u16x8*)&Vb[(rb + row)*256 + hoff + c8];
    #pragma unroll
    for (int e = 0; e < 8; ++e)
      Vt[(c8 + e)*LDV + row] = v[e];
  }

  const int wv = tid >> 6, lane = tid & 63;
  const int g = lane >> 4, r = lane & 15;
  const int q0w = qc*128 + wv*16;

  short8 qh = *(const short8*)&Qh[(rb + q0w + r)*256 + hoff + g*8];
  short8 ql = *(const short8*)&Ql[(rb + q0w + r)*256 + hoff + g*8];
  __syncthreads();

  float m = -1e30f, l = 0.f;
  f32x4 O0 = {0.f,0.f,0.f,0.f}, O1 = {0.f,0.f,0.f,0.f};

  for (int st = 0; st < 16; ++st){
    int key0 = st*32 + (r >> 2)*8 + (r & 3);
    short8 ah0 = *(const short8*)&Khi[key0*LDK + g*8];
    short8 ah1 = *(const short8*)&Khi[(key0+4)*LDK + g*8];
    f32x4 s0 = {0.f,0.f,0.f,0.f}, s1 = {0.f,0.f,0.f,0.f};
    s0 = __builtin_amdgcn_mfma_f32_16x16x32_bf16(ah0, qh, s0, 0,0,0);
    s0 = __builtin_amdgcn_mfma_f32_16x16x32_bf16(ah0, ql, s0, 0,0,0);
    s1 = __builtin_amdgcn_mfma_f32_16x16x32_bf16(ah1, qh, s1, 0,0,0);
    s1 = __builtin_amdgcn_mfma_f32_16x16x32_bf16(ah1, ql, s1, 0,0,0);
    float pv[8] = {s0[0],s0[1],s0[2],s0[3], s1[0],s1[1],s1[2],s1[3]};
    float tm = pv[0];
    #pragma unroll
    for (int j = 1; j < 8; ++j) tm = fmaxf(tm, pv[j]);
    tm = fmaxf(tm, __shfl_xor(tm, 16));
    tm = fmaxf(tm, __shfl_xor(tm, 32));
    float mn = fmaxf(m, tm);
    float ts = 0.f;
    #pragma unroll
    for (int j = 0; j < 8; ++j){ pv[j] = __expf(pv[j] - mn); ts += pv[j]; }
    ts += __shfl_xor(ts, 16);
    ts += __shfl_xor(ts, 32);
    if (__any(mn > m)){
      float corr = __expf(m - mn);
      if (lane < 16) cbuf[wv][lane] = corr;
      asm volatile("s_waitcnt lgkmcnt(0)" ::: "memory");
      f32x4 cf = *(const f32x4*)&cbuf[wv][g*4];
      #pragma unroll
      for (int j = 0; j < 4; ++j){ O0[j] *= cf[j]; O1[j] *= cf[j]; }
      l *= corr;
      m = mn;
    }
    l += ts;
    short8 pa;
    #pragma unroll
    for (int j = 0; j < 8; ++j) pa[j] = (short)f2bf(pv[j]);
    short8 v0 = *(const short8*)&Vt[(size_t)r*LDV + st*32 + g*8];
    short8 v1 = *(const short8*)&Vt[(size_t)(r+16)*LDV + st*32 + g*8];
    O0 = __builtin_amdgcn_mfma_f32_16x16x32_bf16(pa, v0, O0, 0,0,0);
    O1 = __builtin_amdgcn_mfma_f32_16x16x32_bf16(pa, v1, O1, 0,0,0);
  }

  // self-attend tile (targets only: qc>=4 at 128 q/block)
  if (qc >= 4){
    short8 kh8 = *(const short8*)&Kb[(rb + q0w + r)*256 + hoff + g*8];
    f32x4 s = {0.f,0.f,0.f,0.f};
    s = __builtin_amdgcn_mfma_f32_16x16x32_bf16(kh8, qh, s, 0,0,0);
    s = __builtin_amdgcn_mfma_f32_16x16x32_bf16(kh8, ql, s, 0,0,0);
    float pv[8] = {0.f,0.f,0.f,0.f,0.f,0.f,0.f,0.f};
    float tm = -1e30f;
    #pragma unroll
    for (int j = 0; j < 4; ++j){
      bool al_ = (g*4 + j) == r;
      tm = fmaxf(tm, al_ ? s[j] : -1e30f);
    }
    tm = fmaxf(tm, __shfl_xor(tm, 16));
    tm = fmaxf(tm, __shfl_xor(tm, 32));
    float mn = fmaxf(m, tm);
    float ts = 0.f;
    #pragma unroll
    for (int j = 0; j < 4; ++j){
      bool al_ = (g*4 + j) == r;
      pv[j] = al_ ? __expf(s[j] - mn) : 0.f;
      ts += pv[j];
    }
    ts += __shfl_xor(ts, 16);
    ts += __shfl_xor(ts, 32);
    if (__any(mn > m)){
      float corr = __expf(m - mn);
      if (lane < 16) cbuf[wv][lane] = corr;
      asm volatile("s_waitcnt lgkmcnt(0)" ::: "memory");
      f32x4 cf = *(const f32x4*)&cbuf[wv][g*4];
      #pragma unroll
      for (int j = 0; j < 4; ++j){ O0[j] *= cf[j]; O1[j] *= cf[j]; }
      l *= corr;
      m = mn;
    }
    l += ts;
    short8 pa, v0, v1;
    #pragma unroll
    for (int j = 0; j < 8; ++j) pa[j] = (short)f2bf(pv[j]);
    #pragma unroll
    for (int j = 0; j < 4; ++j){
      const unsigned short* vp = &Vb[(rb + q0w + g*4 + j)*256 + hoff];
      v0[j] = (short)vp[r];
      v1[j] = (short)vp[r + 16];
      v0[j+4] = 0; v1[j+4] = 0;
    }
    O0 = __builtin_amdgcn_mfma_f32_16x16x32_bf16(pa, v0, O0, 0,0,0);
    O1 = __builtin_amdgcn_mfma_f32_16x16x32_bf16(pa, v1, O1, 0,0,0);
  }

  float inv = 1.f / l;
  if (lane < 16) cbuf[wv][lane] = inv;
  asm volatile("s_waitcnt lgkmcnt(0)" ::: "memory");
  f32x4 iv = *(const f32x4*)&cbuf[wv][g*4];
  size_t ob = (rb + q0w + g*4)*256 + hoff;
  #pragma unroll
  for (int j = 0; j < 4; ++j){
    unsigned short hh, ll;
    tsplit(O0[j]*iv[j], hh, ll);
    oh[ob + (size_t)j*256 + r] = hh;  ol[ob + (size_t)j*256 + r] = ll;
    tsplit(O1[j]*iv[j], hh, ll);
    oh[ob + (size_t)j*256 + r + 16] = hh;  ol[ob + (size_t)j*256 + r + 16] = ll;
  }
}

// ---------------------------------------------------------------- attention v8 (f32 qkv; fallback)
__global__ __launch_bounds__(1024) void attn_v8(
    const float* __restrict__ qkv, float* __restrict__ o)
{
  constexpr int LDK = 40;
  constexpr int LDV = 520;
  __shared__ unsigned short Khi[512*LDK];
  __shared__ unsigned short Vt[32*LDV];
  __shared__ float cbuf[16][16];

  const int tid = threadIdx.x;
  const int qc = blockIdx.x, h = blockIdx.y, b = blockIdx.z;
  const float* base = qkv + (size_t)b*1024*768;
  const int hoff = h*32;
  const float sc = 0.17677669529663687f;

  #pragma unroll
  for (int t = 0; t < 4; ++t){
    int i = tid + t*1024;
    int row = i >> 3, c4 = (i & 7) * 4;
    float4 kv = *(const float4*)&base[(size_t)row*768 + 256 + hoff + c4];
    float ks[4] = {kv.x, kv.y, kv.z, kv.w};
    u16x4 hk;
    #pragma unroll
    for (int e = 0; e < 4; ++e) hk[e] = f2bf(ks[e]);
    *(u16x4*)&Khi[row*LDK + c4] = hk;
    float4 vv = *(const float4*)&base[(size_t)row*768 + 512 + hoff + c4];
    float vs[4] = {vv.x, vv.y, vv.z, vv.w};
    #pragma unroll
    for (int e = 0; e < 4; ++e)
      Vt[(c4 + e)*LDV + row] = f2bf(vs[e]);
  }

  const int wv = tid >> 6, lane = tid & 63;
  const int g = lane >> 4, r = lane & 15;
  const int q0w = qc*256 + wv*16;

  short8 qh, ql;
  {
    const float* qp = &base[(size_t)(q0w + r)*768 + hoff + g*8];
    float4 a = *(const float4*)qp;
    float4 c = *(const float4*)(qp + 4);
    float xs[8] = {a.x*sc, a.y*sc, a.z*sc, a.w*sc, c.x*sc, c.y*sc, c.z*sc, c.w*sc};
    #pragma unroll
    for (int e = 0; e < 8; ++e){
      unsigned short hb_ = f2bf(xs[e]);
      qh[e] = (short)hb_;
      ql[e] = (short)f2bf(xs[e] - bf2f(hb_));
    }
  }
  __syncthreads();

  float m = -1e30f, l = 0.f;
  f32x4 O0 = {0.f,0.f,0.f,0.f}, O1 = {0.f,0.f,0.f,0.f};

  for (int st = 0; st < 16; ++st){
    int key0 = st*32 + (r >> 2)*8 + (r & 3);
    short8 ah0 = *(const short8*)&Khi[key0*LDK + g*8];
    short8 ah1 = *(const short8*)&Khi[(key0+4)*LDK + g*8];
    f32x4 s0 = {0.f,0.f,0.f,0.f}, s1 = {0.f,0.f,0.f,0.f};
    s0 = __builtin_amdgcn_mfma_f32_16x16x32_bf16(ah0, qh, s0, 0,0,0);
    s0 = __builtin_amdgcn_mfma_f32_16x16x32_bf16(ah0, ql, s0, 0,0,0);
    s1 = __builtin_amdgcn_mfma_f32_16x16x32_bf16(ah1, qh, s1, 0,0,0);
    s1 = __builtin_amdgcn_mfma_f32_16x16x32_bf16(ah1, ql, s1, 0,0,0);
    float pv[8] = {s0[0],s0[1],s0[2],s0[3], s1[0],s1[1],s1[2],s1[3]};
    float tm = pv[0];
    #pragma unroll
    for (int j = 1; j < 8; ++j) tm = fmaxf(tm, pv[j]);
    tm = fmaxf(tm, __shfl_xor(tm, 16));
    tm = fmaxf(tm, __shfl_xor(tm, 32));
    float mn = fmaxf(m, tm);
    float ts = 0.f;
    #pragma unroll
    for (int j = 0; j < 8; ++j){ pv[j] = __expf(pv[j] - mn); ts += pv[j]; }
    ts += __shfl_xor(ts, 16);
    ts += __shfl_xor(ts, 32);
    if (__any(mn > m)){
      float corr = __expf(m - mn);
      if (lane < 16) cbuf[wv][lane] = corr;
      asm volatile("s_waitcnt lgkmcnt(0)" ::: "memory");
      f32x4 cf = *(const f32x4*)&cbuf[wv][g*4];
      #pragma unroll
      for (int j = 0; j < 4; ++j){ O0[j] *= cf[j]; O1[j] *= cf[j]; }
      l *= corr;
      m = mn;
    }
    l += ts;
    short8 pa;
    #pragma unroll
    for (int j = 0; j < 8; ++j) pa[j] = (short)f2bf(pv[j]);
    short8 v0 = *(const short8*)&Vt[(size_t)r*LDV + st*32 + g*8];
    short8 v1 = *(const short8*)&Vt[(size_t)(r+16)*LDV + st*32 + g*8];
    O0 = __builtin_amdgcn_mfma_f32_16x16x32_bf16(pa, v0, O0, 0,0,0);
    O1 = __builtin_amdgcn_mfma_f32_16x16x32_bf16(pa, v1, O1, 0,0,0);
  }

  if (qc >= 2){
    const float* kp = &base[(size_t)(q0w + r)*768 + 256 + hoff + g*8];
    float4 a = *(const float4*)kp;
    float4 c = *(const float4*)(kp + 4);
    float xs[8] = {a.x, a.y, a.z, a.w, c.x, c.y, c.z, c.w};
    short8 kh8;
    #pragma unroll
    for (int e = 0; e < 8; ++e) kh8[e] = (short)f2bf(xs[e]);
    f32x4 s = {0.f,0.f,0.f,0.f};
    s = __builtin_amdgcn_mfma_f32_16x16x32_bf16(kh8, qh, s, 0,0,0);
    s = __builtin_amdgcn_mfma_f32_16x16x32_bf16(kh8, ql, s, 0,0,0);
    float pv[8] = {0.f,0.f,0.f,0.f,0.f,0.f,0.f,0.f};
    float tm = -1e30f;
    #pragma unroll
    for (int j = 0; j < 4; ++j){
      bool al_ = (g*4 + j) == r;
      tm = fmaxf(tm, al_ ? s[j] : -1e30f);
    }
    tm = fmaxf(tm, __shfl_xor(tm, 16));
    tm = fmaxf(tm, __shfl_xor(tm, 32));
    float mn = fmaxf(m, tm);
    float ts = 0.f;
    #pragma unroll
    for (int j = 0; j < 4; ++j){
      bool al_ = (g*4 + j) == r;
      pv[j] = al_ ? __expf(s[j] - mn) : 0.f;
      ts += pv[j];
    }
    ts += __shfl_xor(ts, 16);
    ts += __shfl_xor(ts, 32);
    if (__any(mn > m)){
      float corr = __expf(m - mn);
      if (lane < 16) cbuf[wv][lane] = corr;
      asm volatile("s_waitcnt lgkmcnt(0)" ::: "memory");
      f32x4 cf = *(const f32x4*)&cbuf[wv][g*4];
      #pragma unroll
      for (int j = 0; j < 4; ++j){ O0[j] *= cf[j]; O1[j] *= cf[j]; }
      l *= corr;
      m = mn;
    }
    l += ts;
    short8 pa, v0, v1;
    #pragma unroll
    for (int j = 0; j < 8; ++j) pa[j] = (short)f2bf(pv[j]);
    #pragma unroll
    for (int j = 0; j < 4; ++j){
      const float* vp = &base[(size_t)(q0w + g*4 + j)*768 + 512 + hoff];
      v0[j] = (short)f2bf(vp[r]);
      v1[j] = (short)f2bf(vp[r + 16]);
      v0[j+4] = 0; v1[j+4] = 0;
    }
    O0 = __builtin_amdgcn_mfma_f32_16x16x32_bf16(pa, v0, O0, 0,0,0);
    O1 = __builtin_amdgcn_mfma_f32_16x16x32_bf16(pa, v1, O1, 0,0,0);
  }

  float inv = 1.f / l;
  if (lane < 16) cbuf[wv][lane] = inv;
  asm volatile("s_waitcnt lgkmcnt(0)" ::: "memory");
  f32x4 iv = *(const f32x4*)&cbuf[wv][g*4];
  float* op = o + ((size_t)b*1024 + q0w + g*4)*256 + hoff;
  #pragma unroll
  for (int j = 0; j < 4; ++j){
    op[(size_t)j*256 + r]      = O0[j] * iv[j];
    op[(size_t)j*256 + r + 16] = O1[j] * iv[j];
  }
}

// ---------------------------------------------------------------- launch
extern "C" void kernel_launch(void* const* d_in, const int* in_sizes, int n_in,
                              void* d_out, int out_size, void* d_ws, size_t ws_size,
                              hipStream_t stream)
{
  (void)in_sizes; (void)n_in; (void)out_size;
  const float* xc   = (const float*)d_in[0];
  const float* yc   = (const float*)d_in[1];
  const float* xt   = (const float*)d_in[2];
  const float* eW1  = (const float*)d_in[3];
  const float* eb1  = (const float*)d_in[4];
  const float* eW2  = (const float*)d_in[5];
  const float* eb2  = (const float*)d_in[6];
  const float* Wqkv = (const float*)d_in[7];
  const float* bqkv = (const float*)d_in[8];
  const float* Wo   = (const float*)d_in[9];
  const float* bo   = (const float*)d_in[10];
  const float* ln1g = (const float*)d_in[11];
  const float* ln1b = (const float*)d_in[12];
  const float* ln2g = (const float*)d_in[13];
  const float* ln2b = (const float*)d_in[14];
  const float* Wff1 = (const float*)d_in[15];
  const float* bff1 = (const float*)d_in[16];
  const float* Wff2 = (const float*)d_in[17];
  const float* bff2 = (const float*)d_in[18];

  float* zf = (float*)d_out;            // residual stream [8][1024][256] f32 = 8 MB
  char* ws = (char*)d_ws;

  const size_t MiB = 1024*1024;
  const bool hugews = (ws_size == 0) || (ws_size >= 64*MiB);   // observed ws = 256 MiB

  if (hugews){
    unsigned short* lnh = (unsigned short*)ws;                      // 4 MiB
    unsigned short* lnl = lnh + 4*MiB/2;
    unsigned short* qQh = (unsigned short*)(ws + 8*MiB);
    unsigned short* qQl = (unsigned short*)(ws + 12*MiB);
    unsigned short* qKb = (unsigned short*)(ws + 16*MiB);
    unsigned short* qVb = (unsigned short*)(ws + 20*MiB);
    unsigned short* ffh_b = (unsigned short*)(ws + 8*MiB);          // reuses qkv planes (dead after attn)
    float*          scratch = (float*)(ws + 8*MiB);                 // enc hid
    unsigned short* W = (unsigned short*)(ws + 32*MiB);
    unsigned short* qkvTh = W;                   // 6*196608 per plane
    unsigned short* qkvTl = W + 1179648;
    unsigned short* woTh  = W + 2359296;         // 6*65536
    unsigned short* woTl  = W + 2752512;
    unsigned short* w1Th  = W + 3145728;         // 6*262144
    unsigned short* w1Tl  = W + 4718592;
    unsigned short* w2Th  = W + 6291456;
    unsigned short* w2Tl  = W + 7864320;
    unsigned short* e2Th  = W + 9437184;         // 65536
    unsigned short* e2Tl  = W + 9502720;
    unsigned short* aoh = (unsigned short*)(ws + 52*MiB);           // 4 MiB
    unsigned short* aol = aoh + 4*MiB/2;

    convt<<<dim3(12,8,6), 256, 0, stream>>>(Wqkv, qkvTh, qkvTl, 256, 768);
    convt<<<dim3(4,8,6),  256, 0, stream>>>(Wo,   woTh,  woTl,  256, 256);
    convt<<<dim3(16,8,6), 256, 0, stream>>>(Wff1, w1Th,  w1Tl,  256, 1024);
    convt<<<dim3(4,32,6), 256, 0, stream>>>(Wff2, w2Th,  w2Tl,  1024, 256);
    convt<<<dim3(4,8,1),  256, 0, stream>>>(eW2,  e2Th,  e2Tl,  256, 256);

    encoder_s1<<<8192, 256, 0, stream>>>(xc, yc, xt, eW1, eb1, scratch);
    gemm_mfma<0,1,0,64><<<dim3(4,64), 256, 0, stream>>>(scratch, nullptr, nullptr,
                                                        nullptr, e2Th, e2Tl,
                                                        eb2, nullptr, zf, nullptr,
                                                        nullptr, nullptr, nullptr, 256, 256);

    for (int l=0; l<6; l++){
      unsigned short* qh_ = qkvTh + (size_t)l*196608;
      unsigned short* ql_ = qkvTl + (size_t)l*196608;
      unsigned short* oh_ = woTh  + (size_t)l*65536;
      unsigned short* olw = woTl  + (size_t)l*65536;
      unsigned short* f1h = w1Th  + (size_t)l*262144;
      unsigned short* f1l = w1Tl  + (size_t)l*262144;
      unsigned short* f2h = w2Th  + (size_t)l*262144;
      unsigned short* f2l = w2Tl  + (size_t)l*262144;

      ln_v2b<<<2048, 256, 0, stream>>>(zf, ln1g+l*256, ln1b+l*256, lnh, lnl);
      gemm_mfma<2,1,4,64><<<dim3(12,64), 256, 0, stream>>>(nullptr, lnh, lnl,
                                                           nullptr, qh_, ql_,
                                                           bqkv+l*768, nullptr, nullptr, qQh,
                                                           qQl, qKb, qVb, 768, 256);
      attn_v10<<<dim3(8,8,8), 512, 0, stream>>>(qQh, qQl, qKb, qVb, aoh, aol);
      gemm_mfma<2,1,2,64><<<dim3(4,64), 256, 0, stream>>>(nullptr, aoh, aol,
                                                          nullptr, oh_, olw,
                                                          bo+l*256, zf, zf, nullptr,
                                                          nullptr, nullptr, nullptr, 256, 256);
      ln_v2b<<<2048, 256, 0, stream>>>(zf, ln2g+l*256, ln2b+l*256, lnh, lnl);
      gemm_mfma<2,1,3,128><<<dim3(8,64), 256, 0, stream>>>(nullptr, lnh, lnl,
                                                           nullptr, f1h, f1l,
                                                           bff1+l*1024, nullptr, nullptr, ffh_b,
                                                           nullptr, nullptr, nullptr, 1024, 256);
      gemm_mfma<1,1,2,64><<<dim3(4,64), 256, 0, stream>>>(nullptr, ffh_b, nullptr,
                                                          nullptr, f2h, f2l,
                                                          bff2+l*256, zf, zf, nullptr,
                                                          nullptr, nullptr, nullptr, 256, 1024);
    }
  } else {
    // conservative fallback: all-f32 path (in-kernel split), chunked scratch
    float* hb      = (float*)(ws);
    float* scratch = (float*)(ws + 8*MiB);
    encoder_s1<<<8192, 256, 0, stream>>>(xc, yc, xt, eW1, eb1, hb);
    gemm_mfma<0,0,0,128><<<dim3(2,64), 256, 0, stream>>>(hb, nullptr, nullptr, eW2, nullptr, nullptr,
                                                         eb2, nullptr, zf, nullptr,
                                                         nullptr, nullptr, nullptr, 256, 256);
    for (int l=0; l<6; l++){
      const float* Wq = Wqkv + (size_t)l*256*768;
      const float* Wl = Wo   + (size_t)l*256*256;
      const float* W1 = Wff1 + (size_t)l*256*1024;
      const float* W2 = Wff2 + (size_t)l*1024*256;

      ln_v2<<<2048, 256, 0, stream>>>(zf, ln1g+l*256, ln1b+l*256, hb);
      for (int c=0; c<4; c++){
        float* hrows = hb + (size_t)c*2048*256;
        gemm_mfma<0,0,0,128><<<dim3(6,16), 256, 0, stream>>>(hrows, nullptr, nullptr, Wq, nullptr, nullptr,
                                                             bqkv+l*768, nullptr, scratch, nullptr,
                                                             nullptr, nullptr, nullptr, 768, 256);
        attn_v8<<<dim3(4,8,2), 1024, 0, stream>>>(scratch, hrows);
      }
      gemm_mfma<0,0,2,128><<<dim3(2,64), 256, 0, stream>>>(hb, nullptr, nullptr, Wl, nullptr, nullptr,
                                                           bo+l*256, zf, zf, nullptr,
                                                           nullptr, nullptr, nullptr, 256, 256);
      ln_v2<<<2048, 256, 0, stream>>>(zf, ln2g+l*256, ln2b+l*256, hb);
      for (int c=0; c<4; c++){
        float* hrows = hb + (size_t)c*2048*256;
        float* zrows = zf + (size_t)c*2048*256;
        gemm_mfma<0,0,1,128><<<dim3(8,16), 256, 0, stream>>>(hrows, nullptr, nullptr, W1, nullptr, nullptr,
                                                             bff1+l*1024, nullptr, scratch, nullptr,
                                                             nullptr, nullptr, nullptr, 1024, 256);
        gemm_mfma<0,0,2,128><<<dim3(2,16), 256, 0, stream>>>(scratch, nullptr, nullptr, W2, nullptr, nullptr,
                                                             bff2+l*256, zrows, zrows, nullptr,
                                                             nullptr, nullptr, nullptr, 256, 1024);
      }
    }
  }
}